// Round 1
// baseline (95.889 us; speedup 1.0000x reference)
//
#include <hip/hip_runtime.h>

// Label-smoothing KLDivLoss, sum reduction.
// V=32000, N=4096, smoothing=0.1, padding_idx=0.
// Analytic collapse:
//   base = 0.1/(V-2)
//   row_loss(t!=0) = C - base*(rowsum - y[row,0] - y[row,t]) - 0.9*y[row,t]
//   C = 0.9*ln(0.9) + 0.1*ln(base)
//   rows with t==0 contribute 0.
// Total = sum over rows. Memory-bound: one pass over 524 MB.

#define VOCAB 32000
#define NTOK  4096

static constexpr float  BASEP = 0.1f / (VOCAB - 2);           // 3.1251953e-6
static constexpr double C_ROW = -1.3624258413882367;          // 0.9*ln(0.9)+0.1*ln(0.1/31998)

__global__ __launch_bounds__(256) void ls_row_partial(
    const float* __restrict__ yhat,
    const int*   __restrict__ target,
    float*       __restrict__ partial)
{
    const int row = blockIdx.x;
    const int t   = target[row];                 // scalar broadcast load
    const float* rowp = yhat + (size_t)row * VOCAB;

    float s = 0.f;
    if (t != 0) {                                // block-uniform branch
        const float4* rp4 = reinterpret_cast<const float4*>(rowp);
        // VOCAB/4 = 8000 float4 per row, 256 threads -> 32 iters (last partial)
        #pragma unroll 4
        for (int i = threadIdx.x; i < VOCAB / 4; i += 256) {
            float4 v = rp4[i];
            s += (v.x + v.y) + (v.z + v.w);
        }
    }

    // wave(64)-level shuffle reduce
    #pragma unroll
    for (int off = 32; off > 0; off >>= 1)
        s += __shfl_down(s, off, 64);

    __shared__ float lds[4];                     // 256/64 waves
    const int wid  = threadIdx.x >> 6;
    const int lane = threadIdx.x & 63;
    if (lane == 0) lds[wid] = s;
    __syncthreads();

    if (threadIdx.x == 0) {
        float out = 0.f;
        if (t != 0) {
            const float S  = (lds[0] + lds[1]) + (lds[2] + lds[3]);
            const float y0 = rowp[0];
            const float yt = rowp[t];
            out = (float)C_ROW - BASEP * (S - y0 - yt) - 0.9f * yt;
        }
        partial[row] = out;                      // ws is poisoned: always write
    }
}

__global__ __launch_bounds__(1024) void ls_final_reduce(
    const float* __restrict__ partial,
    float*       __restrict__ out)
{
    float s = 0.f;
    for (int i = threadIdx.x; i < NTOK; i += 1024)
        s += partial[i];

    #pragma unroll
    for (int off = 32; off > 0; off >>= 1)
        s += __shfl_down(s, off, 64);

    __shared__ float lds[16];                    // 1024/64 waves
    const int wid  = threadIdx.x >> 6;
    const int lane = threadIdx.x & 63;
    if (lane == 0) lds[wid] = s;
    __syncthreads();

    if (threadIdx.x == 0) {
        float S = 0.f;
        #pragma unroll
        for (int i = 0; i < 16; ++i) S += lds[i];
        out[0] = S;
    }
}

extern "C" void kernel_launch(void* const* d_in, const int* in_sizes, int n_in,
                              void* d_out, int out_size, void* d_ws, size_t ws_size,
                              hipStream_t stream)
{
    const float* yhat   = (const float*)d_in[0];
    const int*   target = (const int*)d_in[1];
    float*       out    = (float*)d_out;
    float*       part   = (float*)d_ws;          // 4096 floats = 16 KB

    ls_row_partial<<<NTOK, 256, 0, stream>>>(yhat, target, part);
    ls_final_reduce<<<1, 1024, 0, stream>>>(part, out);
}